// Round 1
// baseline (3283.657 us; speedup 1.0000x reference)
//
#include <hip/hip_runtime.h>
#include <math.h>

#define DIMC 512
#define HIDC 2048
#define EC   16
#define BC   8
#define NC   2048
#define CAPC 256
#define BN   (BC * NC)          // 16384 tokens
#define THRESH 0.8f

// ---------------------------------------------------------------- gating ----
// One wave (64 threads) per token. Lanes 0..15 end up owning expert e=lane.
__global__ __launch_bounds__(64) void gate_kernel(const float* __restrict__ x,
                                                  const float* __restrict__ wg,
                                                  float* __restrict__ raw,
                                                  float* __restrict__ weights,
                                                  float* __restrict__ maskf)
{
    int token = blockIdx.x;
    int lane  = threadIdx.x;
    const float* xr = x + (size_t)token * DIMC;

    float acc[EC];
#pragma unroll
    for (int e = 0; e < EC; ++e) acc[e] = 0.f;

    // lane covers dims [lane*8, lane*8+8)
#pragma unroll
    for (int j = 0; j < 8; ++j) {
        int d = lane * 8 + j;
        float xv = xr[d];
        const float* wrow = wg + (size_t)d * EC;
#pragma unroll
        for (int e = 0; e < EC; ++e) acc[e] += xv * wrow[e];
    }
    // butterfly: every lane gets all 16 logits
#pragma unroll
    for (int e = 0; e < EC; ++e) {
#pragma unroll
        for (int off = 32; off >= 1; off >>= 1)
            acc[e] += __shfl_xor(acc[e], off);
    }
    // lane e takes logit e (select chain, constant indices only)
    float logit = acc[0];
#pragma unroll
    for (int e = 1; e < EC; ++e)
        if (lane == e) logit = acc[e];

    // softmax over the 16-lane group
    float m = logit;
#pragma unroll
    for (int off = 8; off >= 1; off >>= 1) m = fmaxf(m, __shfl_xor(m, off, 16));
    float p = expf(logit - m);
    float s = p;
#pragma unroll
    for (int off = 8; off >= 1; off >>= 1) s += __shfl_xor(s, off, 16);
    p = p / s;

    // rank (descending, stable by index) + inclusive cumsum in sorted order
    int lane16 = lane & 15;
    int   rank = 0;
    float cum  = p;
#pragma unroll
    for (int j = 1; j < 16; ++j) {
        float op  = __shfl_xor(p, j, 16);
        int  oidx = lane16 ^ j;
        bool ahead = (op > p) || (op == p && oidx < lane16);
        if (ahead) { rank++; cum += op; }
    }
    bool tm = (cum >= THRESH);
    int kr = tm ? rank : (EC - 1);           // no-crossing => k = E
#pragma unroll
    for (int off = 8; off >= 1; off >>= 1) kr = min(kr, __shfl_xor(kr, off, 16));
    bool sel = (rank <= kr);

    float dsel = sel ? p : 0.f;
    float denom = dsel;
#pragma unroll
    for (int off = 8; off >= 1; off >>= 1) denom += __shfl_xor(denom, off, 16);
    float w = sel ? (p / denom) : 0.f;

    if (lane < EC) {
        size_t o = (size_t)token * EC + lane;
        raw[o]     = p;
        weights[o] = w;
        maskf[o]   = sel ? 1.f : 0.f;
    }
}

// ------------------------------------------------------------- capacity ----
// One wave per (b,e): wave-scan over token order; also density / proxy sums.
__global__ __launch_bounds__(64) void capacity_kernel(const float* __restrict__ raw,
                                                      float* __restrict__ maskf,
                                                      int* __restrict__ pos,
                                                      float* __restrict__ density,
                                                      float* __restrict__ proxy)
{
    int t = blockIdx.x;              // 0..B*E-1
    int b = t / EC, e = t % EC;
    int lane = threadIdx.x;

    int count = 0;
    float rsum = 0.f;
    for (int n0 = 0; n0 < NC; n0 += 64) {
        int n = n0 + lane;
        size_t idx = ((size_t)b * NC + n) * EC + e;
        float mv = maskf[idx];
        rsum += raw[idx];
        unsigned long long bal = __ballot(mv != 0.f);
        int below = __popcll(bal & ((1ull << lane) - 1ull));
        int pval = 0;
        if (mv != 0.f) {
            pval = count + below;                     // exclusive cumsum
            if (pval >= CAPC) { maskf[idx] = 0.f; pval = 0; }
        }
        pos[idx] = pval;
        count += __popcll(bal);
    }
#pragma unroll
    for (int off = 32; off >= 1; off >>= 1) rsum += __shfl_xor(rsum, off);
    if (lane == 0) {
        int admitted = count < CAPC ? count : CAPC;
        density[t] = (float)admitted / (float)NC;
        proxy[t]   = rsum / (float)NC;
    }
}

// pos_tok[b,n] = sum_e pos[b,n,e]   (reference quirk: slot = summed positions)
__global__ void postok_kernel(const int* __restrict__ pos, int* __restrict__ pos_tok)
{
    int t = blockIdx.x * blockDim.x + threadIdx.x;
    if (t >= BN) return;
    const int* pr = pos + (size_t)t * EC;
    int s = 0;
#pragma unroll
    for (int e = 0; e < EC; ++e) s += pr[e];
    pos_tok[t] = s;
}

__global__ void zero_kernel(float4* __restrict__ p, int n4)
{
    int i = blockIdx.x * blockDim.x + threadIdx.x;
    if (i < n4) p[i] = make_float4(0.f, 0.f, 0.f, 0.f);
}

// ------------------------------------------------------------- scatter -----
// expert_inputs[e,b,c,:] += x[b,n,:] for masked (token,e); c may collide -> atomic
__global__ __launch_bounds__(256) void scatter_kernel(const float* __restrict__ x,
                                                      const float* __restrict__ maskf,
                                                      const int* __restrict__ pos_tok,
                                                      float* __restrict__ ei)
{
    int token = blockIdx.x;
    int tid   = threadIdx.x;
    int c = pos_tok[token];
    if (c >= CAPC) return;
    int b = token / NC;
    const float* xr = x + (size_t)token * DIMC;
    float v0 = xr[tid], v1 = xr[tid + 256];
    const float* mr = maskf + (size_t)token * EC;
#pragma unroll
    for (int e = 0; e < EC; ++e) {
        if (mr[e] != 0.f) {
            float* dst = ei + (((size_t)e * BC + b) * CAPC + c) * DIMC;
            atomicAdd(dst + tid, v0);
            atomicAdd(dst + tid + 256, v1);
        }
    }
}

// ---------------------------------------------------------------- GEMM -----
// C[M,N] = act(A[M,K] @ B[K,N]); all row-major; M,N,K multiples of 64/16.
#define TILE 64
#define KT   16
__global__ __launch_bounds__(256) void gemm_kernel(const float* __restrict__ A,
                                                   const float* __restrict__ B,
                                                   float* __restrict__ C,
                                                   int M, int N, int K, int gelu)
{
    __shared__ float As[KT][TILE + 4];
    __shared__ float Bs[KT][TILE + 4];
    int tid = threadIdx.x;
    int tx = tid & 15, ty = tid >> 4;
    int bn = blockIdx.x * TILE, bm = blockIdx.y * TILE;

    float acc[4][4];
#pragma unroll
    for (int i = 0; i < 4; ++i)
#pragma unroll
        for (int j = 0; j < 4; ++j) acc[i][j] = 0.f;

    for (int k0 = 0; k0 < K; k0 += KT) {
        {   // A tile: 64 rows x 16 k, float4 per thread
            int m = tid >> 2, kk = (tid & 3) << 2;
            float4 a = *(const float4*)(A + (size_t)(bm + m) * K + k0 + kk);
            As[kk + 0][m] = a.x; As[kk + 1][m] = a.y;
            As[kk + 2][m] = a.z; As[kk + 3][m] = a.w;
        }
        {   // B tile: 16 k x 64 n, float4 per thread (coalesced)
            int k = tid >> 4, n0 = (tid & 15) << 2;
            *(float4*)&Bs[k][n0] = *(const float4*)(B + (size_t)(k0 + k) * N + bn + n0);
        }
        __syncthreads();
#pragma unroll
        for (int k = 0; k < KT; ++k) {
            float4 a4 = *(const float4*)&As[k][ty << 2];
            float4 b4 = *(const float4*)&Bs[k][tx << 2];
            float av[4] = {a4.x, a4.y, a4.z, a4.w};
            float bv[4] = {b4.x, b4.y, b4.z, b4.w};
#pragma unroll
            for (int ii = 0; ii < 4; ++ii)
#pragma unroll
                for (int jj = 0; jj < 4; ++jj)
                    acc[ii][jj] = fmaf(av[ii], bv[jj], acc[ii][jj]);
        }
        __syncthreads();
    }
#pragma unroll
    for (int ii = 0; ii < 4; ++ii) {
        float4 v;
        float vv[4];
#pragma unroll
        for (int jj = 0; jj < 4; ++jj) {
            float t = acc[ii][jj];
            if (gelu) t = 0.5f * t * (1.f + erff(t * 0.70710678118654752f));
            vv[jj] = t;
        }
        v.x = vv[0]; v.y = vv[1]; v.z = vv[2]; v.w = vv[3];
        *(float4*)(C + (size_t)(bm + (ty << 2) + ii) * N + bn + (tx << 2)) = v;
    }
}

// --------------------------------------------------------------- combine ---
__global__ __launch_bounds__(256) void combine_kernel(const float* __restrict__ eo,
                                                      const float* __restrict__ weights,
                                                      const float* __restrict__ maskf,
                                                      const int* __restrict__ pos_tok,
                                                      float* __restrict__ out)
{
    int token = blockIdx.x;
    int tid   = threadIdx.x;
    int b = token / NC;
    int c = pos_tok[token];
    float a0 = 0.f, a1 = 0.f;
    if (c < CAPC) {
        const float* wr = weights + (size_t)token * EC;
        const float* mr = maskf   + (size_t)token * EC;
#pragma unroll
        for (int e = 0; e < EC; ++e) {
            float wm = wr[e] * mr[e];
            if (wm != 0.f) {
                const float* src = eo + (((size_t)e * BC + b) * CAPC + c) * DIMC;
                a0 += wm * src[tid];
                a1 += wm * src[tid + 256];
            }
        }
    }
    out[(size_t)token * DIMC + tid]       = a0;
    out[(size_t)token * DIMC + tid + 256] = a1;
}

__global__ void loss_kernel(const float* __restrict__ density,
                            const float* __restrict__ proxy,
                            float* __restrict__ out_loss)
{
    __shared__ float sh[BC * EC];
    int t = threadIdx.x;
    sh[t] = density[t] * proxy[t];
    __syncthreads();
    for (int s2 = (BC * EC) / 2; s2 >= 1; s2 >>= 1) {
        if (t < s2) sh[t] += sh[t + s2];
        __syncthreads();
    }
    if (t == 0)
        out_loss[0] = sh[0] * ((float)(EC * EC) / (float)(BC * EC)) * 0.01f;
}

// ---------------------------------------------------------------- launch ---
extern "C" void kernel_launch(void* const* d_in, const int* in_sizes, int n_in,
                              void* d_out, int out_size, void* d_ws, size_t ws_size,
                              hipStream_t stream)
{
    const float* x  = (const float*)d_in[0];
    const float* wg = (const float*)d_in[1];
    const float* w1 = (const float*)d_in[2];
    const float* w2 = (const float*)d_in[3];
    float* out = (float*)d_out;

    char* ws = (char*)d_ws;
    size_t off = 0;
    auto alloc = [&](size_t bytes) -> void* {
        void* p = ws + off;
        off = (off + bytes + 255) & ~(size_t)255;
        return p;
    };
    float* raw      = (float*)alloc((size_t)BN * EC * 4);
    float* weights  = (float*)alloc((size_t)BN * EC * 4);
    float* maskf    = (float*)alloc((size_t)BN * EC * 4);
    int*   pos      = (int*)  alloc((size_t)BN * EC * 4);
    int*   pos_tok  = (int*)  alloc((size_t)BN * 4);
    float* density  = (float*)alloc(BC * EC * 4);
    float* proxy    = (float*)alloc(BC * EC * 4);
    float* ei       = (float*)alloc((size_t)EC * BC * CAPC * DIMC * 4); // 64 MB
    float* eo       = (float*)alloc((size_t)EC * BC * CAPC * DIMC * 4); // 64 MB
    float* hidden   = (float*)alloc((size_t)BC * CAPC * HIDC * 4);      // 16 MB

    (void)in_sizes; (void)n_in; (void)out_size; (void)ws_size;

    // zero expert-input accumulators (ws is poisoned each call)
    int n4 = EC * BC * CAPC * DIMC / 4;
    zero_kernel<<<(n4 + 255) / 256, 256, 0, stream>>>((float4*)ei, n4);

    gate_kernel<<<BN, 64, 0, stream>>>(x, wg, raw, weights, maskf);
    capacity_kernel<<<BC * EC, 64, 0, stream>>>(raw, maskf, pos, density, proxy);
    postok_kernel<<<BN / 256, 256, 0, stream>>>(pos, pos_tok);
    scatter_kernel<<<BN, 256, 0, stream>>>(x, maskf, pos_tok, ei);

    for (int e = 0; e < EC; ++e) {
        const float* Ae = ei + (size_t)e * BC * CAPC * DIMC;
        const float* B1 = w1 + (size_t)e * DIMC * HIDC;
        gemm_kernel<<<dim3(HIDC / TILE, (BC * CAPC) / TILE), 256, 0, stream>>>(
            Ae, B1, hidden, BC * CAPC, HIDC, DIMC, 1);
        const float* B2 = w2 + (size_t)e * HIDC * DIMC;
        float* Ce = eo + (size_t)e * BC * CAPC * DIMC;
        gemm_kernel<<<dim3(DIMC / TILE, (BC * CAPC) / TILE), 256, 0, stream>>>(
            hidden, B2, Ce, BC * CAPC, DIMC, HIDC, 0);
    }

    combine_kernel<<<BN, 256, 0, stream>>>(eo, weights, maskf, pos_tok, out);
    loss_kernel<<<1, BC * EC, 0, stream>>>(density, proxy, out + (size_t)BN * DIMC);
}

// Round 2
// 549.664 us; speedup vs baseline: 5.9739x; 5.9739x over previous
//
#include <hip/hip_runtime.h>
#include <math.h>

#define DIMC 512
#define HIDC 2048
#define EC   16
#define BC   8
#define NC   2048
#define CAPC 256
#define BN   (BC * NC)          // 16384 tokens
#define THRESH 0.8f

typedef unsigned short u16;
typedef __attribute__((ext_vector_type(8))) __bf16 bf16x8;
typedef __attribute__((ext_vector_type(4))) float f32x4;

__device__ __forceinline__ float bf2f(u16 u) {
    union { unsigned i; float f; } v; v.i = ((unsigned)u) << 16; return v.f;
}
__device__ __forceinline__ u16 f2bf(float f) {
    union { float f; unsigned i; } v; v.f = f;
    unsigned r = v.i + 0x7fff + ((v.i >> 16) & 1);
    return (u16)(r >> 16);
}

// ---------------------------------------------------------------- gating ----
__global__ __launch_bounds__(64) void gate_kernel(const float* __restrict__ x,
                                                  const float* __restrict__ wg,
                                                  float* __restrict__ raw,
                                                  float* __restrict__ weights,
                                                  float* __restrict__ maskf)
{
    int token = blockIdx.x;
    int lane  = threadIdx.x;
    const float* xr = x + (size_t)token * DIMC;

    float acc[EC];
#pragma unroll
    for (int e = 0; e < EC; ++e) acc[e] = 0.f;
#pragma unroll
    for (int j = 0; j < 8; ++j) {
        int d = lane * 8 + j;
        float xv = xr[d];
        const float* wrow = wg + (size_t)d * EC;
#pragma unroll
        for (int e = 0; e < EC; ++e) acc[e] += xv * wrow[e];
    }
#pragma unroll
    for (int e = 0; e < EC; ++e) {
#pragma unroll
        for (int off = 32; off >= 1; off >>= 1)
            acc[e] += __shfl_xor(acc[e], off);
    }
    float logit = acc[0];
#pragma unroll
    for (int e = 1; e < EC; ++e)
        if (lane == e) logit = acc[e];

    float m = logit;
#pragma unroll
    for (int off = 8; off >= 1; off >>= 1) m = fmaxf(m, __shfl_xor(m, off, 16));
    float p = expf(logit - m);
    float s = p;
#pragma unroll
    for (int off = 8; off >= 1; off >>= 1) s += __shfl_xor(s, off, 16);
    p = p / s;

    int lane16 = lane & 15;
    int   rank = 0;
    float cum  = p;
#pragma unroll
    for (int j = 1; j < 16; ++j) {
        float op  = __shfl_xor(p, j, 16);
        int  oidx = lane16 ^ j;
        bool ahead = (op > p) || (op == p && oidx < lane16);
        if (ahead) { rank++; cum += op; }
    }
    bool tm = (cum >= THRESH);
    int kr = tm ? rank : (EC - 1);
#pragma unroll
    for (int off = 8; off >= 1; off >>= 1) kr = min(kr, __shfl_xor(kr, off, 16));
    bool sel = (rank <= kr);

    float dsel = sel ? p : 0.f;
    float denom = dsel;
#pragma unroll
    for (int off = 8; off >= 1; off >>= 1) denom += __shfl_xor(denom, off, 16);
    float w = sel ? (p / denom) : 0.f;

    if (lane < EC) {
        size_t o = (size_t)token * EC + lane;
        raw[o]     = p;
        weights[o] = w;
        maskf[o]   = sel ? 1.f : 0.f;
    }
}

// ------------------------------------------------------------- capacity ----
__global__ __launch_bounds__(64) void capacity_kernel(const float* __restrict__ raw,
                                                      float* __restrict__ maskf,
                                                      int* __restrict__ pos,
                                                      float* __restrict__ density,
                                                      float* __restrict__ proxy)
{
    int t = blockIdx.x;
    int b = t / EC, e = t % EC;
    int lane = threadIdx.x;

    int count = 0;
    float rsum = 0.f;
    for (int n0 = 0; n0 < NC; n0 += 64) {
        int n = n0 + lane;
        size_t idx = ((size_t)b * NC + n) * EC + e;
        float mv = maskf[idx];
        rsum += raw[idx];
        unsigned long long bal = __ballot(mv != 0.f);
        int below = __popcll(bal & ((1ull << lane) - 1ull));
        int pval = 0;
        if (mv != 0.f) {
            pval = count + below;
            if (pval >= CAPC) { maskf[idx] = 0.f; pval = 0; }
        }
        pos[idx] = pval;
        count += __popcll(bal);
    }
#pragma unroll
    for (int off = 32; off >= 1; off >>= 1) rsum += __shfl_xor(rsum, off);
    if (lane == 0) {
        int admitted = count < CAPC ? count : CAPC;
        density[t] = (float)admitted / (float)NC;
        proxy[t]   = rsum / (float)NC;
    }
}

__global__ void postok_kernel(const int* __restrict__ pos, int* __restrict__ pos_tok)
{
    int t = blockIdx.x * blockDim.x + threadIdx.x;
    if (t >= BN) return;
    const int* pr = pos + (size_t)t * EC;
    int s = 0;
#pragma unroll
    for (int e = 0; e < EC; ++e) s += pr[e];
    pos_tok[t] = s;
}

__global__ void zero_kernel(float4* __restrict__ p, int n4)
{
    int i = blockIdx.x * blockDim.x + threadIdx.x;
    if (i < n4) p[i] = make_float4(0.f, 0.f, 0.f, 0.f);
}

// ------------------------------------------------------------- scatter -----
__global__ __launch_bounds__(256) void scatter_kernel(const float* __restrict__ x,
                                                      const float* __restrict__ maskf,
                                                      const int* __restrict__ pos_tok,
                                                      float* __restrict__ ei)
{
    int token = blockIdx.x;
    int tid   = threadIdx.x;
    int c = pos_tok[token];
    if (c >= CAPC) return;
    int b = token / NC;
    const float* xr = x + (size_t)token * DIMC;
    float v0 = xr[tid], v1 = xr[tid + 256];
    const float* mr = maskf + (size_t)token * EC;
#pragma unroll
    for (int e = 0; e < EC; ++e) {
        if (mr[e] != 0.f) {
            float* dst = ei + (((size_t)e * BC + b) * CAPC + c) * DIMC;
            atomicAdd(dst + tid, v0);
            atomicAdd(dst + tid + 256, v1);
        }
    }
}

// -------------------------------------------- fp32 -> bf16 bulk convert ----
__global__ __launch_bounds__(256) void cvt_bf16_kernel(const float4* __restrict__ in,
                                                       u16* __restrict__ out, int n8)
{
    int i = blockIdx.x * 256 + threadIdx.x;
    if (i >= n8) return;
    float4 a = in[2 * i], b = in[2 * i + 1];
    uint4 v;
    v.x = (unsigned)f2bf(a.x) | ((unsigned)f2bf(a.y) << 16);
    v.y = (unsigned)f2bf(a.z) | ((unsigned)f2bf(a.w) << 16);
    v.z = (unsigned)f2bf(b.x) | ((unsigned)f2bf(b.y) << 16);
    v.w = (unsigned)f2bf(b.z) | ((unsigned)f2bf(b.w) << 16);
    *(uint4*)(out + (size_t)i * 8) = v;
}

// ------------------------------- weight transpose + convert (per expert) ---
// in: [z][R][C] fp32 row-major  ->  out: [z][C][R] bf16 row-major
__global__ __launch_bounds__(256) void transpose_cvt_kernel(const float* __restrict__ in,
                                                            u16* __restrict__ out,
                                                            int R, int C)
{
    __shared__ float tile[32][33];
    size_t eoff = (size_t)blockIdx.z * R * C;
    const float* ip = in + eoff;
    u16* op = out + eoff;
    int c0 = blockIdx.x * 32, r0 = blockIdx.y * 32;
    int tx = threadIdx.x & 31, ty = threadIdx.x >> 5;   // ty in 0..7
#pragma unroll
    for (int i = 0; i < 32; i += 8)
        tile[ty + i][tx] = ip[(size_t)(r0 + ty + i) * C + c0 + tx];
    __syncthreads();
#pragma unroll
    for (int i = 0; i < 32; i += 8)
        op[(size_t)(c0 + ty + i) * R + r0 + tx] = f2bf(tile[tx][ty + i]);
}

// --------------------------------------------------------- MFMA bf16 GEMM --
// C[e] = act(A[e] @ Bt[e]^T); A: MxK row-major, Bt: NxK row-major (both bf16).
// 128x128 block tile, BK=64, 4 waves (2x2), 4x4 mfma_f32_16x16x32_bf16 each.
// global_load_lds 16B staging with XOR-swizzled LDS chunks.
__device__ __forceinline__ void async_cp16(const u16* g, u16* l) {
    __builtin_amdgcn_global_load_lds(
        (const __attribute__((address_space(1))) unsigned*)g,
        (__attribute__((address_space(3))) unsigned*)l, 16, 0, 0);
}

template<int GELU, int OUTBF16>
__global__ __launch_bounds__(256) void gemm_bt_kernel(
    const u16* __restrict__ A, const u16* __restrict__ Bt, void* __restrict__ Cv,
    int M, int N, int K, long sA, long sB, long sC)
{
    __shared__ __align__(16) u16 lds[2][128 * 64];
    int e = blockIdx.z;
    const u16* Ae = A + (size_t)e * sA;
    const u16* Be = Bt + (size_t)e * sB;
    int bm = blockIdx.y * 128, bn = blockIdx.x * 128;
    int t = threadIdx.x, lane = t & 63, w = t >> 6;
    int wm = (w & 1) * 64, wn = (w >> 1) * 64;
    int q = lane >> 4, m16 = lane & 15;

    f32x4 acc[4][4] = {};

    for (int k0 = 0; k0 < K; k0 += 64) {
        // stage A tile (128 rows x 64 k) : 1024 chunks of 16B, xor-swizzled
#pragma unroll
        for (int i = 0; i < 4; ++i) {
            int l = i * 256 + t, r = l >> 3, s = l & 7, c8 = s ^ (r & 7);
            async_cp16(Ae + (size_t)(bm + r) * K + k0 + c8 * 8, &lds[0][l * 8]);
        }
        // stage Bt tile (128 n-rows x 64 k)
#pragma unroll
        for (int i = 0; i < 4; ++i) {
            int l = i * 256 + t, r = l >> 3, s = l & 7, c8 = s ^ (r & 7);
            async_cp16(Be + (size_t)(bn + r) * K + k0 + c8 * 8, &lds[1][l * 8]);
        }
        __syncthreads();
#pragma unroll
        for (int kk = 0; kk < 64; kk += 32) {
            bf16x8 af[4], bfr[4];
#pragma unroll
            for (int mt = 0; mt < 4; ++mt) {
                int r = wm + mt * 16 + m16, c8 = (kk >> 3) + q;
                af[mt] = *(const bf16x8*)&lds[0][(r * 8 + (c8 ^ (r & 7))) * 8];
            }
#pragma unroll
            for (int nt = 0; nt < 4; ++nt) {
                int r = wn + nt * 16 + m16, c8 = (kk >> 3) + q;
                bfr[nt] = *(const bf16x8*)&lds[1][(r * 8 + (c8 ^ (r & 7))) * 8];
            }
#pragma unroll
            for (int mt = 0; mt < 4; ++mt)
#pragma unroll
                for (int nt = 0; nt < 4; ++nt)
                    acc[mt][nt] = __builtin_amdgcn_mfma_f32_16x16x32_bf16(
                        af[mt], bfr[nt], acc[mt][nt], 0, 0, 0);
        }
        __syncthreads();
    }

    size_t cbase = (size_t)e * sC;
#pragma unroll
    for (int mt = 0; mt < 4; ++mt)
#pragma unroll
        for (int nt = 0; nt < 4; ++nt)
#pragma unroll
            for (int r2 = 0; r2 < 4; ++r2) {
                int row = bm + wm + mt * 16 + q * 4 + r2;
                int col = bn + wn + nt * 16 + m16;
                float v = acc[mt][nt][r2];
                if (GELU) v = 0.5f * v * (1.f + erff(v * 0.70710678118654752f));
                if (OUTBF16) ((u16*)Cv)[cbase + (size_t)row * N + col] = f2bf(v);
                else         ((float*)Cv)[cbase + (size_t)row * N + col] = v;
            }
}

// --------------------------------------------------------------- combine ---
__global__ __launch_bounds__(256) void combine_kernel(const u16* __restrict__ eo,
                                                      const float* __restrict__ weights,
                                                      const float* __restrict__ maskf,
                                                      const int* __restrict__ pos_tok,
                                                      float* __restrict__ out)
{
    int token = blockIdx.x;
    int tid   = threadIdx.x;
    int b = token / NC;
    int c = pos_tok[token];
    float a0 = 0.f, a1 = 0.f;
    if (c < CAPC) {
        const float* wr = weights + (size_t)token * EC;
        const float* mr = maskf   + (size_t)token * EC;
#pragma unroll
        for (int e = 0; e < EC; ++e) {
            float wm = wr[e] * mr[e];
            if (wm != 0.f) {
                const u16* src = eo + (((size_t)e * BC + b) * CAPC + c) * DIMC;
                a0 += wm * bf2f(src[tid]);
                a1 += wm * bf2f(src[tid + 256]);
            }
        }
    }
    out[(size_t)token * DIMC + tid]       = a0;
    out[(size_t)token * DIMC + tid + 256] = a1;
}

__global__ void loss_kernel(const float* __restrict__ density,
                            const float* __restrict__ proxy,
                            float* __restrict__ out_loss)
{
    __shared__ float sh[BC * EC];
    int t = threadIdx.x;
    sh[t] = density[t] * proxy[t];
    __syncthreads();
    for (int s2 = (BC * EC) / 2; s2 >= 1; s2 >>= 1) {
        if (t < s2) sh[t] += sh[t + s2];
        __syncthreads();
    }
    if (t == 0)
        out_loss[0] = sh[0] * ((float)(EC * EC) / (float)(BC * EC)) * 0.01f;
}

// ---------------------------------------------------------------- launch ---
extern "C" void kernel_launch(void* const* d_in, const int* in_sizes, int n_in,
                              void* d_out, int out_size, void* d_ws, size_t ws_size,
                              hipStream_t stream)
{
    const float* x  = (const float*)d_in[0];
    const float* wg = (const float*)d_in[1];
    const float* w1 = (const float*)d_in[2];
    const float* w2 = (const float*)d_in[3];
    float* out = (float*)d_out;

    char* ws = (char*)d_ws;
    size_t off = 0;
    auto alloc = [&](size_t bytes) -> void* {
        void* p = ws + off;
        off = (off + bytes + 255) & ~(size_t)255;
        return p;
    };
    float* raw      = (float*)alloc((size_t)BN * EC * 4);
    float* weights  = (float*)alloc((size_t)BN * EC * 4);
    float* maskf    = (float*)alloc((size_t)BN * EC * 4);
    int*   pos      = (int*)  alloc((size_t)BN * EC * 4);
    int*   pos_tok  = (int*)  alloc((size_t)BN * 4);
    float* density  = (float*)alloc(BC * EC * 4);
    float* proxy    = (float*)alloc(BC * EC * 4);
    // ei fp32 (67 MB) — after conversion this buffer is reused as the bf16
    // hidden buffer for 8 experts (8 * 2048*2048 * 2B = same 67 MB).
    float* ei_f32   = (float*)alloc((size_t)EC * BC * CAPC * DIMC * 4);
    u16*   hidden   = (u16*)ei_f32;
    u16*   ei_bf    = (u16*)alloc((size_t)EC * BC * CAPC * DIMC * 2);  // 33.5 MB
    u16*   w1t      = (u16*)alloc((size_t)EC * DIMC * HIDC * 2);       // 33.5 MB
    u16*   w2t      = (u16*)alloc((size_t)EC * HIDC * DIMC * 2);       // 33.5 MB
    u16*   eo_bf    = (u16*)alloc((size_t)EC * BC * CAPC * DIMC * 2);  // 33.5 MB

    (void)in_sizes; (void)n_in; (void)out_size; (void)ws_size;

    int n4 = EC * BC * CAPC * DIMC / 4;
    zero_kernel<<<(n4 + 255) / 256, 256, 0, stream>>>((float4*)ei_f32, n4);

    // weight transpose+convert: w1 [D][H] -> w1t [H][D]; w2 [H][D] -> w2t [D][H]
    transpose_cvt_kernel<<<dim3(HIDC / 32, DIMC / 32, EC), 256, 0, stream>>>(w1, w1t, DIMC, HIDC);
    transpose_cvt_kernel<<<dim3(DIMC / 32, HIDC / 32, EC), 256, 0, stream>>>(w2, w2t, HIDC, DIMC);

    gate_kernel<<<BN, 64, 0, stream>>>(x, wg, raw, weights, maskf);
    capacity_kernel<<<BC * EC, 64, 0, stream>>>(raw, maskf, pos, density, proxy);
    postok_kernel<<<BN / 256, 256, 0, stream>>>(pos, pos_tok);
    scatter_kernel<<<BN, 256, 0, stream>>>(x, maskf, pos_tok, ei_f32);

    int n8 = EC * BC * CAPC * DIMC / 8;
    cvt_bf16_kernel<<<(n8 + 255) / 256, 256, 0, stream>>>((const float4*)ei_f32, ei_bf, n8);

    // FFN: two groups of 8 experts (hidden buffer holds 8 experts, aliases ei_f32)
    for (int g = 0; g < 2; ++g) {
        const u16* Ag  = ei_bf + (size_t)g * 8 * 2048 * 512;
        const u16* B1g = w1t   + (size_t)g * 8 * 2048 * 512;
        gemm_bt_kernel<1, 1><<<dim3(HIDC / 128, 2048 / 128, 8), 256, 0, stream>>>(
            Ag, B1g, hidden, 2048, HIDC, DIMC,
            (long)2048 * 512, (long)2048 * 512, (long)2048 * 2048);
        const u16* B2g = w2t + (size_t)g * 8 * 512 * 2048;
        u16* Eg = eo_bf + (size_t)g * 8 * 2048 * 512;
        gemm_bt_kernel<0, 1><<<dim3(DIMC / 128, 2048 / 128, 8), 256, 0, stream>>>(
            hidden, B2g, Eg, 2048, DIMC, HIDC,
            (long)2048 * 2048, (long)512 * 2048, (long)2048 * 512);
    }

    combine_kernel<<<BN, 256, 0, stream>>>(eo_bf, weights, maskf, pos_tok, out);
    loss_kernel<<<1, BC * EC, 0, stream>>>(density, proxy, out + (size_t)BN * DIMC);
}

// Round 3
// 527.116 us; speedup vs baseline: 6.2295x; 1.0428x over previous
//
#include <hip/hip_runtime.h>
#include <math.h>

#define DIMC 512
#define HIDC 2048
#define EC   16
#define BC   8
#define NC   2048
#define CAPC 256
#define BN   (BC * NC)          // 16384 tokens
#define THRESH 0.8f

typedef unsigned short u16;
typedef __attribute__((ext_vector_type(8))) __bf16 bf16x8;
typedef __attribute__((ext_vector_type(4))) float f32x4;

__device__ __forceinline__ float bf2f(unsigned u) {
    union { unsigned i; float f; } v; v.i = u << 16; return v.f;
}
__device__ __forceinline__ u16 f2bf(float f) {
    union { float f; unsigned i; } v; v.f = f;
    unsigned r = v.i + 0x7fff + ((v.i >> 16) & 1);
    return (u16)(r >> 16);
}
// tanh-form gelu; |err| < 2e-4 for |x|<1.5 (hidden pre-act std ~0.29)
__device__ __forceinline__ float gelu_f(float x) {
    float u = 0.7978845608028654f * (x + 0.044715f * x * x * x);
    float t = __expf(2.f * u);
    float th = 1.f - 2.f / (t + 1.f);
    return 0.5f * x * (1.f + th);
}

// -------------------------------------------------- init (heads/pos_tok) ---
__global__ void init_kernel(int* __restrict__ heads, int* __restrict__ pos_tok)
{
    int i = blockIdx.x * 256 + threadIdx.x;
    if (i < EC * BC * CAPC) heads[i] = -1;
    if (i < BN) pos_tok[i] = 0;
}

// ------------------------------------------- wg transpose [512][16]->[16][512]
__global__ void wgt_kernel(const float* __restrict__ wg, float* __restrict__ wgt)
{
    int i = blockIdx.x * 256 + threadIdx.x;      // 8192 total
    int e = i >> 9, d = i & 511;
    wgt[i] = wg[d * EC + e];
}

// ---------------------------------------------------------------- logits ----
// one thread per (token, e); x row broadcast across the 16 e-threads
__global__ __launch_bounds__(256) void logits_kernel(const float* __restrict__ x,
                                                     const float* __restrict__ wgt,
                                                     float* __restrict__ logits)
{
    int t = threadIdx.x;
    int token = blockIdx.x * 16 + (t >> 4);
    int e = t & 15;
    const float4* xr = (const float4*)(x + (size_t)token * DIMC);
    const float4* wr = (const float4*)(wgt + (size_t)e * DIMC);
    float acc = 0.f;
#pragma unroll 8
    for (int i = 0; i < DIMC / 4; ++i) {
        float4 a = xr[i], b = wr[i];
        acc += a.x * b.x + a.y * b.y + a.z * b.z + a.w * b.w;
    }
    logits[(size_t)token * EC + e] = acc;
}

// ----------------------------------------------------------- gate epilogue --
// one thread per token: softmax + descending-rank top-p + renorm, in registers
__global__ __launch_bounds__(256) void gate_epi_kernel(const float* __restrict__ logits,
                                                       float* __restrict__ raw,
                                                       float* __restrict__ weights,
                                                       float* __restrict__ maskf)
{
    int token = blockIdx.x * 256 + threadIdx.x;
    const float4* lp = (const float4*)(logits + (size_t)token * EC);
    float p[EC];
    {
        float4 v0 = lp[0], v1 = lp[1], v2 = lp[2], v3 = lp[3];
        p[0]=v0.x; p[1]=v0.y; p[2]=v0.z; p[3]=v0.w;
        p[4]=v1.x; p[5]=v1.y; p[6]=v1.z; p[7]=v1.w;
        p[8]=v2.x; p[9]=v2.y; p[10]=v2.z; p[11]=v2.w;
        p[12]=v3.x; p[13]=v3.y; p[14]=v3.z; p[15]=v3.w;
    }
    float m = p[0];
#pragma unroll
    for (int e = 1; e < EC; ++e) m = fmaxf(m, p[e]);
    float s = 0.f;
#pragma unroll
    for (int e = 0; e < EC; ++e) { p[e] = expf(p[e] - m); s += p[e]; }
    float inv = 1.f / s;
#pragma unroll
    for (int e = 0; e < EC; ++e) p[e] *= inv;

    int rank[EC]; float cum[EC];
#pragma unroll
    for (int e = 0; e < EC; ++e) {
        int r = 0; float c = p[e];
#pragma unroll
        for (int j = 0; j < EC; ++j) {
            if (j == e) continue;
            bool ahead = (p[j] > p[e]) || (p[j] == p[e] && j < e);
            r += ahead ? 1 : 0;
            c += ahead ? p[j] : 0.f;
        }
        rank[e] = r; cum[e] = c;
    }
    int kr = EC - 1;
#pragma unroll
    for (int e = 0; e < EC; ++e)
        if (cum[e] >= THRESH) kr = min(kr, rank[e]);
    float denom = 0.f;
#pragma unroll
    for (int e = 0; e < EC; ++e) denom += (rank[e] <= kr) ? p[e] : 0.f;
    float invd = 1.f / denom;

    float w[EC], mk[EC];
#pragma unroll
    for (int e = 0; e < EC; ++e) {
        bool sel = rank[e] <= kr;
        w[e]  = sel ? p[e] * invd : 0.f;
        mk[e] = sel ? 1.f : 0.f;
    }
    float4* rp = (float4*)(raw + (size_t)token * EC);
    float4* wp = (float4*)(weights + (size_t)token * EC);
    float4* mp = (float4*)(maskf + (size_t)token * EC);
#pragma unroll
    for (int i = 0; i < 4; ++i) {
        rp[i] = make_float4(p[4*i], p[4*i+1], p[4*i+2], p[4*i+3]);
        wp[i] = make_float4(w[4*i], w[4*i+1], w[4*i+2], w[4*i+3]);
        mp[i] = make_float4(mk[4*i], mk[4*i+1], mk[4*i+2], mk[4*i+3]);
    }
}

// ------------------------------------------------------------- capacity ----
// one wave per (b,e); wave-scan cumsum; atomicAdd the summed token slot
__global__ __launch_bounds__(64) void capacity_kernel(const float* __restrict__ raw,
                                                      float* __restrict__ maskf,
                                                      int* __restrict__ pos,
                                                      int* __restrict__ pos_tok,
                                                      float* __restrict__ density,
                                                      float* __restrict__ proxy)
{
    int t = blockIdx.x;
    int b = t / EC, e = t % EC;
    int lane = threadIdx.x;

    int count = 0;
    float rsum = 0.f;
    for (int n0 = 0; n0 < NC; n0 += 64) {
        int n = n0 + lane;
        size_t idx = ((size_t)b * NC + n) * EC + e;
        float mv = maskf[idx];
        rsum += raw[idx];
        unsigned long long bal = __ballot(mv != 0.f);
        int below = __popcll(bal & ((1ull << lane) - 1ull));
        int pval = 0;
        if (mv != 0.f) {
            pval = count + below;
            if (pval >= CAPC) { maskf[idx] = 0.f; pval = 0; }
            else if (pval > 0) atomicAdd(&pos_tok[b * NC + n], pval);
        }
        pos[idx] = pval;
        count += __popcll(bal);
    }
#pragma unroll
    for (int off = 32; off >= 1; off >>= 1) rsum += __shfl_xor(rsum, off);
    if (lane == 0) {
        int admitted = count < CAPC ? count : CAPC;
        density[t] = (float)admitted / (float)NC;
        proxy[t]   = rsum / (float)NC;
    }
}

// -------------------------------------------------- per-slot linked lists --
__global__ __launch_bounds__(256) void build_kernel(const float* __restrict__ maskf,
                                                    const int* __restrict__ pos,
                                                    const int* __restrict__ pos_tok,
                                                    int* __restrict__ heads,
                                                    int* __restrict__ nxt,
                                                    int* __restrict__ node_tok)
{
    int id = blockIdx.x * 256 + threadIdx.x;     // token*16 + e
    int token = id >> 4, e = id & 15;
    if (maskf[id] == 0.f) return;
    int c = pos_tok[token];
    if (c >= CAPC) return;
    int b = token >> 11;                          // NC = 2048
    int slot = (e * BC + b) * CAPC + c;
    int node = (e * BC + b) * CAPC + pos[id];     // unique (e,b,pos)
    node_tok[node] = token;
    nxt[node] = atomicExch(&heads[slot], node);
}

// ------------------------------------------ gather -> expert inputs (bf16) --
// one wave per slot; walks the list, fp32 accumulate, bf16 write. Empty -> 0.
__global__ __launch_bounds__(256) void gather_ei_kernel(const float* __restrict__ x,
                                                        const int* __restrict__ heads,
                                                        const int* __restrict__ nxt,
                                                        const int* __restrict__ node_tok,
                                                        u16* __restrict__ ei)
{
    int slot = blockIdx.x * 4 + (threadIdx.x >> 6);   // (e*BC+b)*CAPC + c
    int lane = threadIdx.x & 63;
    float a[8] = {0,0,0,0,0,0,0,0};
    int node = heads[slot];
    while (node >= 0) {
        const float4* xr = (const float4*)(x + (size_t)node_tok[node] * DIMC) + lane * 2;
        float4 v0 = xr[0], v1 = xr[1];
        a[0]+=v0.x; a[1]+=v0.y; a[2]+=v0.z; a[3]+=v0.w;
        a[4]+=v1.x; a[5]+=v1.y; a[6]+=v1.z; a[7]+=v1.w;
        node = nxt[node];
    }
    uint4 v;
    v.x = (unsigned)f2bf(a[0]) | ((unsigned)f2bf(a[1]) << 16);
    v.y = (unsigned)f2bf(a[2]) | ((unsigned)f2bf(a[3]) << 16);
    v.z = (unsigned)f2bf(a[4]) | ((unsigned)f2bf(a[5]) << 16);
    v.w = (unsigned)f2bf(a[6]) | ((unsigned)f2bf(a[7]) << 16);
    *(uint4*)(ei + (size_t)slot * DIMC + lane * 8) = v;
}

// ------------------------------- weight transpose + convert (per expert) ---
__global__ __launch_bounds__(256) void transpose_cvt_kernel(const float* __restrict__ in,
                                                            u16* __restrict__ out,
                                                            int R, int C)
{
    __shared__ float tile[32][33];
    size_t eoff = (size_t)blockIdx.z * R * C;
    const float* ip = in + eoff;
    u16* op = out + eoff;
    int c0 = blockIdx.x * 32, r0 = blockIdx.y * 32;
    int tx = threadIdx.x & 31, ty = threadIdx.x >> 5;
#pragma unroll
    for (int i = 0; i < 32; i += 8)
        tile[ty + i][tx] = ip[(size_t)(r0 + ty + i) * C + c0 + tx];
    __syncthreads();
#pragma unroll
    for (int i = 0; i < 32; i += 8)
        op[(size_t)(c0 + ty + i) * R + r0 + tx] = f2bf(tile[tx][ty + i]);
}

// --------------------------------------------------------- MFMA bf16 GEMM --
__device__ __forceinline__ void async_cp16(const u16* g, u16* l) {
    __builtin_amdgcn_global_load_lds(
        (const __attribute__((address_space(1))) unsigned*)g,
        (__attribute__((address_space(3))) unsigned*)l, 16, 0, 0);
}

template<int GELU>
__global__ __launch_bounds__(256) void gemm_bt_kernel(
    const u16* __restrict__ A, const u16* __restrict__ Bt, u16* __restrict__ C,
    int M, int N, int K, long sA, long sB, long sC)
{
    __shared__ __align__(16) u16 lds[2][128 * 64];
    int e = blockIdx.z;
    int bm = blockIdx.y * 128, bn = blockIdx.x * 128;
    int t = threadIdx.x, lane = t & 63, w = t >> 6;
    int wm = (w & 1) * 64, wn = (w >> 1) * 64;
    int q = lane >> 4, m16 = lane & 15;

    // hoisted staging pointers (advance by 64 elements per K-iter)
    const u16* gA[4]; const u16* gB[4]; u16 *lA[4], *lB[4];
#pragma unroll
    for (int i = 0; i < 4; ++i) {
        int l = i * 256 + t, r = l >> 3, s = l & 7, c8 = s ^ (r & 7);
        gA[i] = A + (size_t)e * sA + (size_t)(bm + r) * K + c8 * 8;
        gB[i] = Bt + (size_t)e * sB + (size_t)(bn + r) * K + c8 * 8;
        lA[i] = &lds[0][l * 8];
        lB[i] = &lds[1][l * 8];
    }
    // hoisted fragment LDS offsets (K-invariant)
    int aoff[4][2], boff[4][2];
#pragma unroll
    for (int i = 0; i < 4; ++i) {
        int ra = wm + i * 16 + m16, rb = wn + i * 16 + m16;
#pragma unroll
        for (int h = 0; h < 2; ++h) {
            int c8 = h * 4 + q;
            aoff[i][h] = (ra * 8 + (c8 ^ (ra & 7))) * 8;
            boff[i][h] = (rb * 8 + (c8 ^ (rb & 7))) * 8;
        }
    }

    f32x4 acc[4][4] = {};

    for (int k0 = 0; k0 < K; k0 += 64) {
#pragma unroll
        for (int i = 0; i < 4; ++i) {
            async_cp16(gA[i], lA[i]);
            async_cp16(gB[i], lB[i]);
            gA[i] += 64; gB[i] += 64;
        }
        __syncthreads();
#pragma unroll
        for (int h = 0; h < 2; ++h) {
            bf16x8 af[4], bfr[4];
#pragma unroll
            for (int mt = 0; mt < 4; ++mt) af[mt] = *(const bf16x8*)&lds[0][aoff[mt][h]];
#pragma unroll
            for (int nt = 0; nt < 4; ++nt) bfr[nt] = *(const bf16x8*)&lds[1][boff[nt][h]];
#pragma unroll
            for (int mt = 0; mt < 4; ++mt)
#pragma unroll
                for (int nt = 0; nt < 4; ++nt)
                    acc[mt][nt] = __builtin_amdgcn_mfma_f32_16x16x32_bf16(
                        af[mt], bfr[nt], acc[mt][nt], 0, 0, 0);
        }
        __syncthreads();
    }

    size_t cbase = (size_t)e * sC;
#pragma unroll
    for (int mt = 0; mt < 4; ++mt)
#pragma unroll
        for (int nt = 0; nt < 4; ++nt)
#pragma unroll
            for (int r2 = 0; r2 < 4; ++r2) {
                int row = bm + wm + mt * 16 + q * 4 + r2;
                int col = bn + wn + nt * 16 + m16;
                float v = acc[mt][nt][r2];
                if (GELU) v = gelu_f(v);
                C[cbase + (size_t)row * N + col] = f2bf(v);
            }
}

// --------------------------------------------------------------- combine ---
__global__ __launch_bounds__(256) void combine_kernel(const u16* __restrict__ eo,
                                                      const float* __restrict__ weights,
                                                      const float* __restrict__ maskf,
                                                      const int* __restrict__ pos_tok,
                                                      float* __restrict__ out)
{
    int token = blockIdx.x;
    int tid   = threadIdx.x;
    int b = token >> 11;
    int c = pos_tok[token];
    float a0 = 0.f, a1 = 0.f;
    if (c < CAPC) {
        const float* wr = weights + (size_t)token * EC;
        const float* mr = maskf   + (size_t)token * EC;
#pragma unroll
        for (int e = 0; e < EC; ++e) {
            float wm = wr[e] * mr[e];
            if (wm != 0.f) {
                const u16* src = eo + (((size_t)e * BC + b) * CAPC + c) * DIMC;
                unsigned u = *(const unsigned*)(src + 2 * tid);
                a0 += wm * bf2f(u & 0xffffu);
                a1 += wm * bf2f(u >> 16);
            }
        }
    }
    *(float2*)(out + (size_t)token * DIMC + 2 * tid) = make_float2(a0, a1);
}

__global__ void loss_kernel(const float* __restrict__ density,
                            const float* __restrict__ proxy,
                            float* __restrict__ out_loss)
{
    __shared__ float sh[BC * EC];
    int t = threadIdx.x;
    sh[t] = density[t] * proxy[t];
    __syncthreads();
    for (int s2 = (BC * EC) / 2; s2 >= 1; s2 >>= 1) {
        if (t < s2) sh[t] += sh[t + s2];
        __syncthreads();
    }
    if (t == 0)
        out_loss[0] = sh[0] * ((float)(EC * EC) / (float)(BC * EC)) * 0.01f;
}

// ---------------------------------------------------------------- launch ---
extern "C" void kernel_launch(void* const* d_in, const int* in_sizes, int n_in,
                              void* d_out, int out_size, void* d_ws, size_t ws_size,
                              hipStream_t stream)
{
    const float* x  = (const float*)d_in[0];
    const float* wg = (const float*)d_in[1];
    const float* w1 = (const float*)d_in[2];
    const float* w2 = (const float*)d_in[3];
    float* out = (float*)d_out;

    char* ws = (char*)d_ws;
    size_t off = 0;
    auto alloc = [&](size_t bytes) -> void* {
        void* p = ws + off;
        off = (off + bytes + 255) & ~(size_t)255;
        return p;
    };
    float* raw      = (float*)alloc((size_t)BN * EC * 4);
    float* weights  = (float*)alloc((size_t)BN * EC * 4);
    float* maskf    = (float*)alloc((size_t)BN * EC * 4);
    int*   pos      = (int*)  alloc((size_t)BN * EC * 4);
    int*   pos_tok  = (int*)  alloc((size_t)BN * 4);
    int*   heads    = (int*)  alloc((size_t)EC * BC * CAPC * 4);
    int*   nxt      = (int*)  alloc((size_t)EC * BC * CAPC * 4);
    int*   node_tok = (int*)  alloc((size_t)EC * BC * CAPC * 4);
    float* density  = (float*)alloc(BC * EC * 4);
    float* proxy    = (float*)alloc(BC * EC * 4);
    float* logits   = (float*)alloc((size_t)BN * EC * 4);
    float* wgt      = (float*)alloc((size_t)EC * DIMC * 4);
    u16*   ei_bf    = (u16*)alloc((size_t)EC * BC * CAPC * DIMC * 2);
    u16*   w1t      = (u16*)alloc((size_t)EC * DIMC * HIDC * 2);
    u16*   w2t      = (u16*)alloc((size_t)EC * HIDC * DIMC * 2);
    u16*   eo_bf    = (u16*)alloc((size_t)EC * BC * CAPC * DIMC * 2);
    // hidden takes the rest; full-size (16 experts) if it fits, else 2 groups
    size_t hid_full = (size_t)EC * BC * CAPC * HIDC * 2;     // 128 MiB
    int ngroups = (ws_size - off >= hid_full) ? 1 : 2;
    int EG = EC / ngroups;
    u16* hidden = (u16*)alloc((size_t)EG * BC * CAPC * HIDC * 2);

    (void)in_sizes; (void)n_in; (void)out_size;

    init_kernel<<<(EC * BC * CAPC + 255) / 256, 256, 0, stream>>>(heads, pos_tok);
    wgt_kernel<<<EC * DIMC / 256, 256, 0, stream>>>(wg, wgt);
    transpose_cvt_kernel<<<dim3(HIDC / 32, DIMC / 32, EC), 256, 0, stream>>>(w1, w1t, DIMC, HIDC);
    transpose_cvt_kernel<<<dim3(DIMC / 32, HIDC / 32, EC), 256, 0, stream>>>(w2, w2t, HIDC, DIMC);

    logits_kernel<<<BN / 16, 256, 0, stream>>>(x, wgt, logits);
    gate_epi_kernel<<<BN / 256, 256, 0, stream>>>(logits, raw, weights, maskf);
    capacity_kernel<<<BC * EC, 64, 0, stream>>>(raw, maskf, pos, pos_tok, density, proxy);
    build_kernel<<<BN * EC / 256, 256, 0, stream>>>(maskf, pos, pos_tok, heads, nxt, node_tok);
    gather_ei_kernel<<<EC * BC * CAPC / 4, 256, 0, stream>>>(x, heads, nxt, node_tok, ei_bf);

    for (int g = 0; g < ngroups; ++g) {
        const u16* Ag  = ei_bf + (size_t)g * EG * BC * CAPC * DIMC;
        const u16* B1g = w1t   + (size_t)g * EG * DIMC * HIDC;
        gemm_bt_kernel<1><<<dim3(HIDC / 128, (BC * CAPC) / 128, EG), 256, 0, stream>>>(
            Ag, B1g, hidden, BC * CAPC, HIDC, DIMC,
            (long)BC * CAPC * DIMC, (long)HIDC * DIMC, (long)BC * CAPC * HIDC);
        const u16* B2g = w2t + (size_t)g * EG * HIDC * DIMC;
        u16* Eg = eo_bf + (size_t)g * EG * BC * CAPC * DIMC;
        gemm_bt_kernel<0><<<dim3(DIMC / 128, (BC * CAPC) / 128, EG), 256, 0, stream>>>(
            hidden, B2g, Eg, BC * CAPC, DIMC, HIDC,
            (long)BC * CAPC * HIDC, (long)DIMC * HIDC, (long)BC * CAPC * DIMC);
    }

    combine_kernel<<<BN, 256, 0, stream>>>(eo_bf, weights, maskf, pos_tok, out);
    loss_kernel<<<1, BC * EC, 0, stream>>>(density, proxy, out + (size_t)BN * DIMC);
}

// Round 4
// 518.519 us; speedup vs baseline: 6.3328x; 1.0166x over previous
//
#include <hip/hip_runtime.h>
#include <math.h>

#define DIMC 512
#define HIDC 2048
#define EC   16
#define BC   8
#define NC   2048
#define CAPC 256
#define BN   (BC * NC)          // 16384 tokens
#define THRESH 0.8f

typedef unsigned short u16;
typedef __attribute__((ext_vector_type(8))) __bf16 bf16x8;
typedef __attribute__((ext_vector_type(4))) float f32x4;

__device__ __forceinline__ float bf2f(unsigned u) {
    union { unsigned i; float f; } v; v.i = u << 16; return v.f;
}
__device__ __forceinline__ u16 f2bf(float f) {
    union { float f; unsigned i; } v; v.f = f;
    unsigned r = v.i + 0x7fff + ((v.i >> 16) & 1);
    return (u16)(r >> 16);
}
// tanh-form gelu; |err| < 2e-4 for |x|<1.5 (hidden pre-act std ~0.29)
__device__ __forceinline__ float gelu_f(float x) {
    float u = 0.7978845608028654f * (x + 0.044715f * x * x * x);
    float t = __expf(2.f * u);
    float th = 1.f - 2.f / (t + 1.f);
    return 0.5f * x * (1.f + th);
}

// -------------------------------------------------- init (heads/pos_tok) ---
__global__ void init_kernel(int* __restrict__ heads, int* __restrict__ pos_tok)
{
    int i = blockIdx.x * 256 + threadIdx.x;
    if (i < EC * BC * CAPC) heads[i] = -1;
    if (i < BN) pos_tok[i] = 0;
}

// ------------------------------------------- wg transpose [512][16]->[16][512]
__global__ void wgt_kernel(const float* __restrict__ wg, float* __restrict__ wgt)
{
    int i = blockIdx.x * 256 + threadIdx.x;      // 8192 total
    int e = i >> 9, d = i & 511;
    wgt[i] = wg[d * EC + e];
}

// ------------------------------------------------------ fused gate kernel ---
// 256 threads = 16 tokens x 16 experts. Dot with 4 independent accumulators
// (ILP), then 16 lanes run the per-token softmax/top-p epilogue from LDS.
__global__ __launch_bounds__(256) void gate_kernel(const float* __restrict__ x,
                                                   const float* __restrict__ wgt,
                                                   float* __restrict__ raw,
                                                   float* __restrict__ weights,
                                                   float* __restrict__ maskf)
{
    __shared__ float lg[16][17];
    int t = threadIdx.x;
    int tok16 = t >> 4, e = t & 15;
    int token0 = blockIdx.x * 16;
    const float4* xr = (const float4*)(x + (size_t)(token0 + tok16) * DIMC);
    const float4* wr = (const float4*)(wgt + (size_t)e * DIMC);

    float a0 = 0.f, a1 = 0.f, a2 = 0.f, a3 = 0.f;
#pragma unroll 2
    for (int i = 0; i < 128; i += 4) {
        float4 xa = xr[i], xb = xr[i+1], xc = xr[i+2], xd = xr[i+3];
        float4 wa = wr[i], wb = wr[i+1], wc = wr[i+2], wd = wr[i+3];
        a0 = fmaf(xa.w, wa.w, fmaf(xa.z, wa.z, fmaf(xa.y, wa.y, fmaf(xa.x, wa.x, a0))));
        a1 = fmaf(xb.w, wb.w, fmaf(xb.z, wb.z, fmaf(xb.y, wb.y, fmaf(xb.x, wb.x, a1))));
        a2 = fmaf(xc.w, wc.w, fmaf(xc.z, wc.z, fmaf(xc.y, wc.y, fmaf(xc.x, wc.x, a2))));
        a3 = fmaf(xd.w, wd.w, fmaf(xd.z, wd.z, fmaf(xd.y, wd.y, fmaf(xd.x, wd.x, a3))));
    }
    lg[tok16][e] = (a0 + a1) + (a2 + a3);
    __syncthreads();
    if (t < 16) {
        int token = token0 + t;
        float p[EC];
#pragma unroll
        for (int j = 0; j < EC; ++j) p[j] = lg[t][j];

        float m = p[0];
#pragma unroll
        for (int j = 1; j < EC; ++j) m = fmaxf(m, p[j]);
        float s = 0.f;
#pragma unroll
        for (int j = 0; j < EC; ++j) { p[j] = expf(p[j] - m); s += p[j]; }
        float inv = 1.f / s;
#pragma unroll
        for (int j = 0; j < EC; ++j) p[j] *= inv;

        int rank[EC]; float cum[EC];
#pragma unroll
        for (int a = 0; a < EC; ++a) {
            int r = 0; float c = p[a];
#pragma unroll
            for (int j = 0; j < EC; ++j) {
                if (j == a) continue;
                bool ahead = (p[j] > p[a]) || (p[j] == p[a] && j < a);
                r += ahead ? 1 : 0;
                c += ahead ? p[j] : 0.f;
            }
            rank[a] = r; cum[a] = c;
        }
        int kr = EC - 1;
#pragma unroll
        for (int a = 0; a < EC; ++a)
            if (cum[a] >= THRESH) kr = min(kr, rank[a]);
        float denom = 0.f;
#pragma unroll
        for (int a = 0; a < EC; ++a) denom += (rank[a] <= kr) ? p[a] : 0.f;
        float invd = 1.f / denom;

        float w[EC], mk[EC];
#pragma unroll
        for (int a = 0; a < EC; ++a) {
            bool sel = rank[a] <= kr;
            w[a]  = sel ? p[a] * invd : 0.f;
            mk[a] = sel ? 1.f : 0.f;
        }
        float4* rp = (float4*)(raw + (size_t)token * EC);
        float4* wp = (float4*)(weights + (size_t)token * EC);
        float4* mp = (float4*)(maskf + (size_t)token * EC);
#pragma unroll
        for (int i = 0; i < 4; ++i) {
            rp[i] = make_float4(p[4*i], p[4*i+1], p[4*i+2], p[4*i+3]);
            wp[i] = make_float4(w[4*i], w[4*i+1], w[4*i+2], w[4*i+3]);
            mp[i] = make_float4(mk[4*i], mk[4*i+1], mk[4*i+2], mk[4*i+3]);
        }
    }
}

// ------------------------------------------------------------- capacity ----
// one wave per (b,e); wave-scan cumsum, software-pipelined loads (prefetch
// next chunk before processing current -- loads don't depend on the scan).
__global__ __launch_bounds__(64) void capacity_kernel(const float* __restrict__ raw,
                                                      float* __restrict__ maskf,
                                                      int* __restrict__ pos,
                                                      int* __restrict__ pos_tok,
                                                      float* __restrict__ density,
                                                      float* __restrict__ proxy)
{
    int t = blockIdx.x;
    int b = t / EC, e = t % EC;
    int lane = threadIdx.x;

    size_t idx = ((size_t)b * NC + lane) * EC + e;
    const size_t step = (size_t)64 * EC;
    float mv = maskf[idx];
    float rv = raw[idx];

    int count = 0;
    float rsum = 0.f;
    for (int n0 = 0; n0 < NC; n0 += 64) {
        float mn = 0.f, rn = 0.f;
        if (n0 + 64 < NC) { mn = maskf[idx + step]; rn = raw[idx + step]; }

        rsum += rv;
        unsigned long long bal = __ballot(mv != 0.f);
        int below = __popcll(bal & ((1ull << lane) - 1ull));
        int pval = 0;
        if (mv != 0.f) {
            pval = count + below;
            if (pval >= CAPC) { maskf[idx] = 0.f; pval = 0; }
            else if (pval > 0) atomicAdd(&pos_tok[b * NC + n0 + lane], pval);
        }
        pos[idx] = pval;
        count += __popcll(bal);

        idx += step; mv = mn; rv = rn;
    }
#pragma unroll
    for (int off = 32; off >= 1; off >>= 1) rsum += __shfl_xor(rsum, off);
    if (lane == 0) {
        int admitted = count < CAPC ? count : CAPC;
        density[t] = (float)admitted / (float)NC;
        proxy[t]   = rsum / (float)NC;
    }
}

// -------------------------------------------------- per-slot linked lists --
__global__ __launch_bounds__(256) void build_kernel(const float* __restrict__ maskf,
                                                    const int* __restrict__ pos,
                                                    const int* __restrict__ pos_tok,
                                                    int* __restrict__ heads,
                                                    int* __restrict__ nxt,
                                                    int* __restrict__ node_tok)
{
    int id = blockIdx.x * 256 + threadIdx.x;     // token*16 + e
    int token = id >> 4, e = id & 15;
    if (maskf[id] == 0.f) return;
    int c = pos_tok[token];
    if (c >= CAPC) return;
    int b = token >> 11;                          // NC = 2048
    int slot = (e * BC + b) * CAPC + c;
    int node = (e * BC + b) * CAPC + pos[id];     // unique (e,b,pos)
    node_tok[node] = token;
    nxt[node] = atomicExch(&heads[slot], node);
}

// ------------------------------------------ gather -> expert inputs (bf16) --
__global__ __launch_bounds__(256) void gather_ei_kernel(const float* __restrict__ x,
                                                        const int* __restrict__ heads,
                                                        const int* __restrict__ nxt,
                                                        const int* __restrict__ node_tok,
                                                        u16* __restrict__ ei)
{
    int slot = blockIdx.x * 4 + (threadIdx.x >> 6);   // (e*BC+b)*CAPC + c
    int lane = threadIdx.x & 63;
    float a[8] = {0,0,0,0,0,0,0,0};
    int node = heads[slot];
    while (node >= 0) {
        const float4* xr = (const float4*)(x + (size_t)node_tok[node] * DIMC) + lane * 2;
        float4 v0 = xr[0], v1 = xr[1];
        a[0]+=v0.x; a[1]+=v0.y; a[2]+=v0.z; a[3]+=v0.w;
        a[4]+=v1.x; a[5]+=v1.y; a[6]+=v1.z; a[7]+=v1.w;
        node = nxt[node];
    }
    uint4 v;
    v.x = (unsigned)f2bf(a[0]) | ((unsigned)f2bf(a[1]) << 16);
    v.y = (unsigned)f2bf(a[2]) | ((unsigned)f2bf(a[3]) << 16);
    v.z = (unsigned)f2bf(a[4]) | ((unsigned)f2bf(a[5]) << 16);
    v.w = (unsigned)f2bf(a[6]) | ((unsigned)f2bf(a[7]) << 16);
    *(uint4*)(ei + (size_t)slot * DIMC + lane * 8) = v;
}

// ------------------------------- weight transpose + convert (per expert) ---
// 64x64 tile; float4 reads, bf16x8 (uint4) writes.
__global__ __launch_bounds__(256) void transpose_cvt_kernel(const float* __restrict__ in,
                                                            u16* __restrict__ out,
                                                            int R, int C)
{
    __shared__ float tile[64][65];
    size_t eoff = (size_t)blockIdx.z * R * C;
    int c0 = blockIdx.x * 64, r0 = blockIdx.y * 64;
    int tid = threadIdx.x;
    int rr = tid >> 4;              // 0..15
    int cc = (tid & 15) * 4;        // 0..60
#pragma unroll
    for (int i = 0; i < 4; ++i) {
        float4 v = *(const float4*)(in + eoff + (size_t)(r0 + rr + 16 * i) * C + c0 + cc);
        tile[rr + 16 * i][cc + 0] = v.x;
        tile[rr + 16 * i][cc + 1] = v.y;
        tile[rr + 16 * i][cc + 2] = v.z;
        tile[rr + 16 * i][cc + 3] = v.w;
    }
    __syncthreads();
    int c = tid >> 2;               // 0..63
    int r8 = (tid & 3) * 16;        // 0,16,32,48
    u16 buf[16];
#pragma unroll
    for (int j = 0; j < 16; ++j) buf[j] = f2bf(tile[r8 + j][c]);
    u16* op = out + eoff + (size_t)(c0 + c) * R + r0 + r8;
    *(uint4*)(op)     = *(uint4*)&buf[0];
    *(uint4*)(op + 8) = *(uint4*)&buf[8];
}

// --------------------------------------------------------- MFMA bf16 GEMM --
// Double-buffered LDS (64 KB): one barrier per K-iter; stage k+1 overlaps
// compute k.
__device__ __forceinline__ void async_cp16(const u16* g, u16* l) {
    __builtin_amdgcn_global_load_lds(
        (const __attribute__((address_space(1))) unsigned*)g,
        (__attribute__((address_space(3))) unsigned*)l, 16, 0, 0);
}

template<int GELU>
__global__ __launch_bounds__(256) void gemm_bt_kernel(
    const u16* __restrict__ A, const u16* __restrict__ Bt, u16* __restrict__ C,
    int M, int N, int K, long sA, long sB, long sC)
{
    __shared__ __align__(16) u16 lds[2][2][128 * 64];   // [buf][op]
    int e = blockIdx.z;
    int bm = blockIdx.y * 128, bn = blockIdx.x * 128;
    int t = threadIdx.x, lane = t & 63, w = t >> 6;
    int wm = (w & 1) * 64, wn = (w >> 1) * 64;
    int q = lane >> 4, m16 = lane & 15;

    const u16* gA[4]; const u16* gB[4]; int lofs[4];
#pragma unroll
    for (int i = 0; i < 4; ++i) {
        int l = i * 256 + t, r = l >> 3, s = l & 7, c8 = s ^ (r & 7);
        gA[i] = A + (size_t)e * sA + (size_t)(bm + r) * K + c8 * 8;
        gB[i] = Bt + (size_t)e * sB + (size_t)(bn + r) * K + c8 * 8;
        lofs[i] = l * 8;
    }
    int aoff[4][2], boff[4][2];
#pragma unroll
    for (int i = 0; i < 4; ++i) {
        int ra = wm + i * 16 + m16, rb = wn + i * 16 + m16;
#pragma unroll
        for (int h = 0; h < 2; ++h) {
            int c8 = h * 4 + q;
            aoff[i][h] = (ra * 8 + (c8 ^ (ra & 7))) * 8;
            boff[i][h] = (rb * 8 + (c8 ^ (rb & 7))) * 8;
        }
    }

    // prologue: stage first tile into buf 0
#pragma unroll
    for (int i = 0; i < 4; ++i) {
        async_cp16(gA[i], &lds[0][0][lofs[i]]);
        async_cp16(gB[i], &lds[0][1][lofs[i]]);
        gA[i] += 64; gB[i] += 64;
    }

    f32x4 acc[4][4] = {};
    int nk = K >> 6;
    for (int ki = 0; ki < nk; ++ki) {
        int cur = ki & 1, nx = cur ^ 1;
        __syncthreads();                       // waits cur's loads (vmcnt 0)
        if (ki + 1 < nk) {
#pragma unroll
            for (int i = 0; i < 4; ++i) {
                async_cp16(gA[i], &lds[nx][0][lofs[i]]);
                async_cp16(gB[i], &lds[nx][1][lofs[i]]);
                gA[i] += 64; gB[i] += 64;
            }
        }
#pragma unroll
        for (int h = 0; h < 2; ++h) {
            bf16x8 af[4], bfr[4];
#pragma unroll
            for (int mt = 0; mt < 4; ++mt) af[mt] = *(const bf16x8*)&lds[cur][0][aoff[mt][h]];
#pragma unroll
            for (int nt = 0; nt < 4; ++nt) bfr[nt] = *(const bf16x8*)&lds[cur][1][boff[nt][h]];
#pragma unroll
            for (int mt = 0; mt < 4; ++mt)
#pragma unroll
                for (int nt = 0; nt < 4; ++nt)
                    acc[mt][nt] = __builtin_amdgcn_mfma_f32_16x16x32_bf16(
                        af[mt], bfr[nt], acc[mt][nt], 0, 0, 0);
        }
    }

    size_t cbase = (size_t)e * sC;
#pragma unroll
    for (int mt = 0; mt < 4; ++mt)
#pragma unroll
        for (int nt = 0; nt < 4; ++nt)
#pragma unroll
            for (int r2 = 0; r2 < 4; ++r2) {
                int row = bm + wm + mt * 16 + q * 4 + r2;
                int col = bn + wn + nt * 16 + m16;
                float v = acc[mt][nt][r2];
                if (GELU) v = gelu_f(v);
                C[cbase + (size_t)row * N + col] = f2bf(v);
            }
}

// --------------------------------------------------------------- combine ---
__global__ __launch_bounds__(256) void combine_kernel(const u16* __restrict__ eo,
                                                      const float* __restrict__ weights,
                                                      const float* __restrict__ maskf,
                                                      const int* __restrict__ pos_tok,
                                                      float* __restrict__ out)
{
    int token = blockIdx.x;
    int tid   = threadIdx.x;
    int b = token >> 11;
    int c = pos_tok[token];
    float a0 = 0.f, a1 = 0.f;
    if (c < CAPC) {
        const float* wr = weights + (size_t)token * EC;
        const float* mr = maskf   + (size_t)token * EC;
#pragma unroll
        for (int e = 0; e < EC; ++e) {
            float wm = wr[e] * mr[e];
            if (wm != 0.f) {
                const u16* src = eo + (((size_t)e * BC + b) * CAPC + c) * DIMC;
                unsigned u = *(const unsigned*)(src + 2 * tid);
                a0 += wm * bf2f(u & 0xffffu);
                a1 += wm * bf2f(u >> 16);
            }
        }
    }
    *(float2*)(out + (size_t)token * DIMC + 2 * tid) = make_float2(a0, a1);
}

__global__ void loss_kernel(const float* __restrict__ density,
                            const float* __restrict__ proxy,
                            float* __restrict__ out_loss)
{
    __shared__ float sh[BC * EC];
    int t = threadIdx.x;
    sh[t] = density[t] * proxy[t];
    __syncthreads();
    for (int s2 = (BC * EC) / 2; s2 >= 1; s2 >>= 1) {
        if (t < s2) sh[t] += sh[t + s2];
        __syncthreads();
    }
    if (t == 0)
        out_loss[0] = sh[0] * ((float)(EC * EC) / (float)(BC * EC)) * 0.01f;
}

// ---------------------------------------------------------------- launch ---
extern "C" void kernel_launch(void* const* d_in, const int* in_sizes, int n_in,
                              void* d_out, int out_size, void* d_ws, size_t ws_size,
                              hipStream_t stream)
{
    const float* x  = (const float*)d_in[0];
    const float* wg = (const float*)d_in[1];
    const float* w1 = (const float*)d_in[2];
    const float* w2 = (const float*)d_in[3];
    float* out = (float*)d_out;

    char* ws = (char*)d_ws;
    size_t off = 0;
    auto alloc = [&](size_t bytes) -> void* {
        void* p = ws + off;
        off = (off + bytes + 255) & ~(size_t)255;
        return p;
    };
    float* raw      = (float*)alloc((size_t)BN * EC * 4);
    float* weights  = (float*)alloc((size_t)BN * EC * 4);
    float* maskf    = (float*)alloc((size_t)BN * EC * 4);
    int*   pos      = (int*)  alloc((size_t)BN * EC * 4);
    int*   pos_tok  = (int*)  alloc((size_t)BN * 4);
    int*   heads    = (int*)  alloc((size_t)EC * BC * CAPC * 4);
    int*   nxt      = (int*)  alloc((size_t)EC * BC * CAPC * 4);
    int*   node_tok = (int*)  alloc((size_t)EC * BC * CAPC * 4);
    float* density  = (float*)alloc(BC * EC * 4);
    float* proxy    = (float*)alloc(BC * EC * 4);
    float* wgt      = (float*)alloc((size_t)EC * DIMC * 4);
    u16*   ei_bf    = (u16*)alloc((size_t)EC * BC * CAPC * DIMC * 2);
    u16*   w1t      = (u16*)alloc((size_t)EC * DIMC * HIDC * 2);
    u16*   w2t      = (u16*)alloc((size_t)EC * HIDC * DIMC * 2);
    u16*   eo_bf    = (u16*)alloc((size_t)EC * BC * CAPC * DIMC * 2);
    // hidden takes the rest; full-size (16 experts) if it fits, else 2 groups
    size_t hid_full = (size_t)EC * BC * CAPC * HIDC * 2;     // 128 MiB
    int ngroups = (ws_size - off >= hid_full) ? 1 : 2;
    int EG = EC / ngroups;
    u16* hidden = (u16*)alloc((size_t)EG * BC * CAPC * HIDC * 2);

    (void)in_sizes; (void)n_in; (void)out_size;

    init_kernel<<<(EC * BC * CAPC + 255) / 256, 256, 0, stream>>>(heads, pos_tok);
    wgt_kernel<<<EC * DIMC / 256, 256, 0, stream>>>(wg, wgt);
    transpose_cvt_kernel<<<dim3(HIDC / 64, DIMC / 64, EC), 256, 0, stream>>>(w1, w1t, DIMC, HIDC);
    transpose_cvt_kernel<<<dim3(DIMC / 64, HIDC / 64, EC), 256, 0, stream>>>(w2, w2t, HIDC, DIMC);

    gate_kernel<<<BN / 16, 256, 0, stream>>>(x, wgt, raw, weights, maskf);
    capacity_kernel<<<BC * EC, 64, 0, stream>>>(raw, maskf, pos, pos_tok, density, proxy);
    build_kernel<<<BN * EC / 256, 256, 0, stream>>>(maskf, pos, pos_tok, heads, nxt, node_tok);
    gather_ei_kernel<<<EC * BC * CAPC / 4, 256, 0, stream>>>(x, heads, nxt, node_tok, ei_bf);

    for (int g = 0; g < ngroups; ++g) {
        const u16* Ag  = ei_bf + (size_t)g * EG * BC * CAPC * DIMC;
        const u16* B1g = w1t   + (size_t)g * EG * DIMC * HIDC;
        gemm_bt_kernel<1><<<dim3(HIDC / 128, (BC * CAPC) / 128, EG), 256, 0, stream>>>(
            Ag, B1g, hidden, BC * CAPC, HIDC, DIMC,
            (long)BC * CAPC * DIMC, (long)HIDC * DIMC, (long)BC * CAPC * HIDC);
        const u16* B2g = w2t + (size_t)g * EG * HIDC * DIMC;
        u16* Eg = eo_bf + (size_t)g * EG * BC * CAPC * DIMC;
        gemm_bt_kernel<0><<<dim3(DIMC / 128, (BC * CAPC) / 128, EG), 256, 0, stream>>>(
            hidden, B2g, Eg, BC * CAPC, DIMC, HIDC,
            (long)BC * CAPC * HIDC, (long)DIMC * HIDC, (long)BC * CAPC * DIMC);
    }

    combine_kernel<<<BN, 256, 0, stream>>>(eo_bf, weights, maskf, pos_tok, out);
    loss_kernel<<<1, BC * EC, 0, stream>>>(density, proxy, out + (size_t)BN * DIMC);
}

// Round 5
// 470.082 us; speedup vs baseline: 6.9853x; 1.1030x over previous
//
#include <hip/hip_runtime.h>
#include <math.h>

#define DIMC 512
#define HIDC 2048
#define EC   16
#define BC   8
#define NC   2048
#define CAPC 256
#define BN   (BC * NC)          // 16384 tokens
#define THRESH 0.8f

typedef unsigned short u16;
typedef __attribute__((ext_vector_type(8))) __bf16 bf16x8;
typedef __attribute__((ext_vector_type(4))) float f32x4;

__device__ __forceinline__ float bf2f(unsigned u) {
    union { unsigned i; float f; } v; v.i = u << 16; return v.f;
}
__device__ __forceinline__ u16 f2bf(float f) {
    union { float f; unsigned i; } v; v.f = f;
    unsigned r = v.i + 0x7fff + ((v.i >> 16) & 1);
    return (u16)(r >> 16);
}
// tanh-form gelu; |err| < 2e-4 for |x|<1.5 (hidden pre-act std ~0.29)
__device__ __forceinline__ float gelu_f(float x) {
    float u = 0.7978845608028654f * (x + 0.044715f * x * x * x);
    float t = __expf(2.f * u);
    float th = 1.f - 2.f / (t + 1.f);
    return 0.5f * x * (1.f + th);
}

// -------------------------------------------------- init (heads/pos_tok) ---
__global__ void init_kernel(int* __restrict__ heads, int* __restrict__ pos_tok)
{
    int i = blockIdx.x * 256 + threadIdx.x;
    if (i < EC * BC * CAPC) heads[i] = -1;
    if (i < BN) pos_tok[i] = 0;
}

// ------------------------------------------------------ fused gate kernel ---
// 256 threads = 16 tokens x 16 experts (lanes 0-15 of each 16-group share a
// token). wg staged+transposed into padded LDS (stride 516 -> worst 2-way
// bank alias = free). x read as 16-lane broadcast from global. Epilogue via
// width-16 shuffles on ALL threads; coalesced writes.
__global__ __launch_bounds__(256) void gate_kernel(const float* __restrict__ x,
                                                   const float* __restrict__ wg,
                                                   float* __restrict__ raw,
                                                   float* __restrict__ weights,
                                                   float* __restrict__ maskf)
{
    __shared__ float wlds[16][516];
    __shared__ float lg[16][16];
    int t = threadIdx.x;
    int tok16 = t >> 4, e = t & 15;
    int token = blockIdx.x * 16 + tok16;

    // stage wg [512][16] -> wlds[e][d] (transpose), coalesced float4 reads
    {
        const float4* wg4 = (const float4*)wg;
#pragma unroll
        for (int j = 0; j < 8; ++j) {
            int idx4 = j * 256 + t;            // covers 2048 float4s
            float4 v = wg4[idx4];
            int d  = idx4 >> 2;                // element row (dim)
            int e0 = (idx4 & 3) * 4;           // starting expert
            wlds[e0 + 0][d] = v.x;
            wlds[e0 + 1][d] = v.y;
            wlds[e0 + 2][d] = v.z;
            wlds[e0 + 3][d] = v.w;
        }
    }
    __syncthreads();

    // dot: x broadcast (global), w from LDS
    const float4* xr = (const float4*)(x + (size_t)token * DIMC);
    const float4* wl = (const float4*)&wlds[e][0];
    float a0 = 0.f, a1 = 0.f, a2 = 0.f, a3 = 0.f;
#pragma unroll 4
    for (int i = 0; i < 128; i += 4) {
        float4 xa = xr[i], xb = xr[i+1], xc = xr[i+2], xd = xr[i+3];
        float4 wa = wl[i], wb = wl[i+1], wc = wl[i+2], wd = wl[i+3];
        a0 = fmaf(xa.w, wa.w, fmaf(xa.z, wa.z, fmaf(xa.y, wa.y, fmaf(xa.x, wa.x, a0))));
        a1 = fmaf(xb.w, wb.w, fmaf(xb.z, wb.z, fmaf(xb.y, wb.y, fmaf(xb.x, wb.x, a1))));
        a2 = fmaf(xc.w, wc.w, fmaf(xc.z, wc.z, fmaf(xc.y, wc.y, fmaf(xc.x, wc.x, a2))));
        a3 = fmaf(xd.w, wd.w, fmaf(xd.z, wd.z, fmaf(xd.y, wd.y, fmaf(xd.x, wd.x, a3))));
    }
    float logit = (a0 + a1) + (a2 + a3);

    // softmax over the 16-lane token group
    float m = logit;
#pragma unroll
    for (int off = 8; off >= 1; off >>= 1) m = fmaxf(m, __shfl_xor(m, off, 16));
    float p = expf(logit - m);
    float s = p;
#pragma unroll
    for (int off = 8; off >= 1; off >>= 1) s += __shfl_xor(s, off, 16);
    p = p / s;

    // rank (descending, stable by index) + cumsum-to-me in sorted order
    int rank = 0;
    float cum = p;
#pragma unroll
    for (int j = 1; j < 16; ++j) {
        float op = __shfl_xor(p, j, 16);
        int oidx = e ^ j;
        bool ahead = (op > p) || (op == p && oidx < e);
        if (ahead) { rank++; cum += op; }
    }
    bool tm = (cum >= THRESH);
    int kr = tm ? rank : (EC - 1);
#pragma unroll
    for (int off = 8; off >= 1; off >>= 1) kr = min(kr, __shfl_xor(kr, off, 16));
    bool sel = (rank <= kr);

    float dsel = sel ? p : 0.f;
    float denom = dsel;
#pragma unroll
    for (int off = 8; off >= 1; off >>= 1) denom += __shfl_xor(denom, off, 16);
    float w = sel ? (p / denom) : 0.f;

    size_t o = (size_t)token * EC + e;
    raw[o]     = p;
    weights[o] = w;
    maskf[o]   = sel ? 1.f : 0.f;
    (void)lg;
}

// ------------------------------------------------------------- capacity ----
// one wave per (b,e); wave-scan cumsum, software-pipelined loads.
__global__ __launch_bounds__(64) void capacity_kernel(const float* __restrict__ raw,
                                                      float* __restrict__ maskf,
                                                      int* __restrict__ pos,
                                                      int* __restrict__ pos_tok,
                                                      float* __restrict__ density,
                                                      float* __restrict__ proxy)
{
    int t = blockIdx.x;
    int b = t / EC, e = t % EC;
    int lane = threadIdx.x;

    size_t idx = ((size_t)b * NC + lane) * EC + e;
    const size_t step = (size_t)64 * EC;
    float mv = maskf[idx];
    float rv = raw[idx];

    int count = 0;
    float rsum = 0.f;
    for (int n0 = 0; n0 < NC; n0 += 64) {
        float mn = 0.f, rn = 0.f;
        if (n0 + 64 < NC) { mn = maskf[idx + step]; rn = raw[idx + step]; }

        rsum += rv;
        unsigned long long bal = __ballot(mv != 0.f);
        int below = __popcll(bal & ((1ull << lane) - 1ull));
        int pval = 0;
        if (mv != 0.f) {
            pval = count + below;
            if (pval >= CAPC) { maskf[idx] = 0.f; pval = 0; }
            else if (pval > 0) atomicAdd(&pos_tok[b * NC + n0 + lane], pval);
        }
        pos[idx] = pval;
        count += __popcll(bal);

        idx += step; mv = mn; rv = rn;
    }
#pragma unroll
    for (int off = 32; off >= 1; off >>= 1) rsum += __shfl_xor(rsum, off);
    if (lane == 0) {
        int admitted = count < CAPC ? count : CAPC;
        density[t] = (float)admitted / (float)NC;
        proxy[t]   = rsum / (float)NC;
    }
}

// -------------------------------------------------- per-slot linked lists --
__global__ __launch_bounds__(256) void build_kernel(const float* __restrict__ maskf,
                                                    const int* __restrict__ pos,
                                                    const int* __restrict__ pos_tok,
                                                    int* __restrict__ heads,
                                                    int* __restrict__ nxt,
                                                    int* __restrict__ node_tok)
{
    int id = blockIdx.x * 256 + threadIdx.x;     // token*16 + e
    int token = id >> 4, e = id & 15;
    if (maskf[id] == 0.f) return;
    int c = pos_tok[token];
    if (c >= CAPC) return;
    int b = token >> 11;                          // NC = 2048
    int slot = (e * BC + b) * CAPC + c;
    int node = (e * BC + b) * CAPC + pos[id];     // unique (e,b,pos)
    node_tok[node] = token;
    nxt[node] = atomicExch(&heads[slot], node);
}

// ------------------------------------------ gather -> expert inputs (bf16) --
__global__ __launch_bounds__(256) void gather_ei_kernel(const float* __restrict__ x,
                                                        const int* __restrict__ heads,
                                                        const int* __restrict__ nxt,
                                                        const int* __restrict__ node_tok,
                                                        u16* __restrict__ ei)
{
    int slot = blockIdx.x * 4 + (threadIdx.x >> 6);   // (e*BC+b)*CAPC + c
    int lane = threadIdx.x & 63;
    float a[8] = {0,0,0,0,0,0,0,0};
    int node = heads[slot];
    while (node >= 0) {
        const float4* xr = (const float4*)(x + (size_t)node_tok[node] * DIMC) + lane * 2;
        float4 v0 = xr[0], v1 = xr[1];
        a[0]+=v0.x; a[1]+=v0.y; a[2]+=v0.z; a[3]+=v0.w;
        a[4]+=v1.x; a[5]+=v1.y; a[6]+=v1.z; a[7]+=v1.w;
        node = nxt[node];
    }
    uint4 v;
    v.x = (unsigned)f2bf(a[0]) | ((unsigned)f2bf(a[1]) << 16);
    v.y = (unsigned)f2bf(a[2]) | ((unsigned)f2bf(a[3]) << 16);
    v.z = (unsigned)f2bf(a[4]) | ((unsigned)f2bf(a[5]) << 16);
    v.w = (unsigned)f2bf(a[6]) | ((unsigned)f2bf(a[7]) << 16);
    *(uint4*)(ei + (size_t)slot * DIMC + lane * 8) = v;
}

// ------------------------------- weight transpose + convert (per expert) ---
__global__ __launch_bounds__(256) void transpose_cvt_kernel(const float* __restrict__ in,
                                                            u16* __restrict__ out,
                                                            int R, int C)
{
    __shared__ float tile[64][65];
    size_t eoff = (size_t)blockIdx.z * R * C;
    int c0 = blockIdx.x * 64, r0 = blockIdx.y * 64;
    int tid = threadIdx.x;
    int rr = tid >> 4;              // 0..15
    int cc = (tid & 15) * 4;        // 0..60
#pragma unroll
    for (int i = 0; i < 4; ++i) {
        float4 v = *(const float4*)(in + eoff + (size_t)(r0 + rr + 16 * i) * C + c0 + cc);
        tile[rr + 16 * i][cc + 0] = v.x;
        tile[rr + 16 * i][cc + 1] = v.y;
        tile[rr + 16 * i][cc + 2] = v.z;
        tile[rr + 16 * i][cc + 3] = v.w;
    }
    __syncthreads();
    int c = tid >> 2;               // 0..63
    int r8 = (tid & 3) * 16;        // 0,16,32,48
    u16 buf[16];
#pragma unroll
    for (int j = 0; j < 16; ++j) buf[j] = f2bf(tile[r8 + j][c]);
    u16* op = out + eoff + (size_t)(c0 + c) * R + r0 + r8;
    *(uint4*)(op)     = *(uint4*)&buf[0];
    *(uint4*)(op + 8) = *(uint4*)&buf[8];
}

// --------------------------------------------------------- MFMA bf16 GEMM --
__device__ __forceinline__ void async_cp16(const u16* g, u16* l) {
    __builtin_amdgcn_global_load_lds(
        (const __attribute__((address_space(1))) unsigned*)g,
        (__attribute__((address_space(3))) unsigned*)l, 16, 0, 0);
}

template<int GELU>
__global__ __launch_bounds__(256) void gemm_bt_kernel(
    const u16* __restrict__ A, const u16* __restrict__ Bt, u16* __restrict__ C,
    int M, int N, int K, long sA, long sB, long sC)
{
    __shared__ __align__(16) u16 lds[2][2][128 * 64];   // [buf][op]
    int e = blockIdx.z;
    int bm = blockIdx.y * 128, bn = blockIdx.x * 128;
    int t = threadIdx.x, lane = t & 63, w = t >> 6;
    int wm = (w & 1) * 64, wn = (w >> 1) * 64;
    int q = lane >> 4, m16 = lane & 15;

    const u16* gA[4]; const u16* gB[4]; int lofs[4];
#pragma unroll
    for (int i = 0; i < 4; ++i) {
        int l = i * 256 + t, r = l >> 3, s = l & 7, c8 = s ^ (r & 7);
        gA[i] = A + (size_t)e * sA + (size_t)(bm + r) * K + c8 * 8;
        gB[i] = Bt + (size_t)e * sB + (size_t)(bn + r) * K + c8 * 8;
        lofs[i] = l * 8;
    }
    int aoff[4][2], boff[4][2];
#pragma unroll
    for (int i = 0; i < 4; ++i) {
        int ra = wm + i * 16 + m16, rb = wn + i * 16 + m16;
#pragma unroll
        for (int h = 0; h < 2; ++h) {
            int c8 = h * 4 + q;
            aoff[i][h] = (ra * 8 + (c8 ^ (ra & 7))) * 8;
            boff[i][h] = (rb * 8 + (c8 ^ (rb & 7))) * 8;
        }
    }

#pragma unroll
    for (int i = 0; i < 4; ++i) {
        async_cp16(gA[i], &lds[0][0][lofs[i]]);
        async_cp16(gB[i], &lds[0][1][lofs[i]]);
        gA[i] += 64; gB[i] += 64;
    }

    f32x4 acc[4][4] = {};
    int nk = K >> 6;
    for (int ki = 0; ki < nk; ++ki) {
        int cur = ki & 1, nx = cur ^ 1;
        __syncthreads();
        if (ki + 1 < nk) {
#pragma unroll
            for (int i = 0; i < 4; ++i) {
                async_cp16(gA[i], &lds[nx][0][lofs[i]]);
                async_cp16(gB[i], &lds[nx][1][lofs[i]]);
                gA[i] += 64; gB[i] += 64;
            }
        }
#pragma unroll
        for (int h = 0; h < 2; ++h) {
            bf16x8 af[4], bfr[4];
#pragma unroll
            for (int mt = 0; mt < 4; ++mt) af[mt] = *(const bf16x8*)&lds[cur][0][aoff[mt][h]];
#pragma unroll
            for (int nt = 0; nt < 4; ++nt) bfr[nt] = *(const bf16x8*)&lds[cur][1][boff[nt][h]];
#pragma unroll
            for (int mt = 0; mt < 4; ++mt)
#pragma unroll
                for (int nt = 0; nt < 4; ++nt)
                    acc[mt][nt] = __builtin_amdgcn_mfma_f32_16x16x32_bf16(
                        af[mt], bfr[nt], acc[mt][nt], 0, 0, 0);
        }
    }

    size_t cbase = (size_t)e * sC;
#pragma unroll
    for (int mt = 0; mt < 4; ++mt)
#pragma unroll
        for (int nt = 0; nt < 4; ++nt)
#pragma unroll
            for (int r2 = 0; r2 < 4; ++r2) {
                int row = bm + wm + mt * 16 + q * 4 + r2;
                int col = bn + wn + nt * 16 + m16;
                float v = acc[mt][nt][r2];
                if (GELU) v = gelu_f(v);
                C[cbase + (size_t)row * N + col] = f2bf(v);
            }
}

// --------------------------------------------------------------- combine ---
__global__ __launch_bounds__(256) void combine_kernel(const u16* __restrict__ eo,
                                                      const float* __restrict__ weights,
                                                      const float* __restrict__ maskf,
                                                      const int* __restrict__ pos_tok,
                                                      float* __restrict__ out)
{
    int token = blockIdx.x;
    int tid   = threadIdx.x;
    int b = token >> 11;
    int c = pos_tok[token];
    float a0 = 0.f, a1 = 0.f;
    if (c < CAPC) {
        const float* wr = weights + (size_t)token * EC;
        const float* mr = maskf   + (size_t)token * EC;
#pragma unroll
        for (int e = 0; e < EC; ++e) {
            float wm = wr[e] * mr[e];
            if (wm != 0.f) {
                const u16* src = eo + (((size_t)e * BC + b) * CAPC + c) * DIMC;
                unsigned u = *(const unsigned*)(src + 2 * tid);
                a0 += wm * bf2f(u & 0xffffu);
                a1 += wm * bf2f(u >> 16);
            }
        }
    }
    *(float2*)(out + (size_t)token * DIMC + 2 * tid) = make_float2(a0, a1);
}

__global__ void loss_kernel(const float* __restrict__ density,
                            const float* __restrict__ proxy,
                            float* __restrict__ out_loss)
{
    __shared__ float sh[BC * EC];
    int t = threadIdx.x;
    sh[t] = density[t] * proxy[t];
    __syncthreads();
    for (int s2 = (BC * EC) / 2; s2 >= 1; s2 >>= 1) {
        if (t < s2) sh[t] += sh[t + s2];
        __syncthreads();
    }
    if (t == 0)
        out_loss[0] = sh[0] * ((float)(EC * EC) / (float)(BC * EC)) * 0.01f;
}

// ---------------------------------------------------------------- launch ---
extern "C" void kernel_launch(void* const* d_in, const int* in_sizes, int n_in,
                              void* d_out, int out_size, void* d_ws, size_t ws_size,
                              hipStream_t stream)
{
    const float* x  = (const float*)d_in[0];
    const float* wg = (const float*)d_in[1];
    const float* w1 = (const float*)d_in[2];
    const float* w2 = (const float*)d_in[3];
    float* out = (float*)d_out;

    char* ws = (char*)d_ws;
    size_t off = 0;
    auto alloc = [&](size_t bytes) -> void* {
        void* p = ws + off;
        off = (off + bytes + 255) & ~(size_t)255;
        return p;
    };
    float* raw      = (float*)alloc((size_t)BN * EC * 4);
    float* weights  = (float*)alloc((size_t)BN * EC * 4);
    float* maskf    = (float*)alloc((size_t)BN * EC * 4);
    int*   pos      = (int*)  alloc((size_t)BN * EC * 4);
    int*   pos_tok  = (int*)  alloc((size_t)BN * 4);
    int*   heads    = (int*)  alloc((size_t)EC * BC * CAPC * 4);
    int*   nxt      = (int*)  alloc((size_t)EC * BC * CAPC * 4);
    int*   node_tok = (int*)  alloc((size_t)EC * BC * CAPC * 4);
    float* density  = (float*)alloc(BC * EC * 4);
    float* proxy    = (float*)alloc(BC * EC * 4);
    u16*   ei_bf    = (u16*)alloc((size_t)EC * BC * CAPC * DIMC * 2);
    u16*   w1t      = (u16*)alloc((size_t)EC * DIMC * HIDC * 2);
    u16*   w2t      = (u16*)alloc((size_t)EC * HIDC * DIMC * 2);
    u16*   eo_bf    = (u16*)alloc((size_t)EC * BC * CAPC * DIMC * 2);
    size_t hid_full = (size_t)EC * BC * CAPC * HIDC * 2;     // 128 MiB
    int ngroups = (ws_size - off >= hid_full) ? 1 : 2;
    int EG = EC / ngroups;
    u16* hidden = (u16*)alloc((size_t)EG * BC * CAPC * HIDC * 2);

    (void)in_sizes; (void)n_in; (void)out_size;

    init_kernel<<<(EC * BC * CAPC + 255) / 256, 256, 0, stream>>>(heads, pos_tok);
    transpose_cvt_kernel<<<dim3(HIDC / 64, DIMC / 64, EC), 256, 0, stream>>>(w1, w1t, DIMC, HIDC);
    transpose_cvt_kernel<<<dim3(DIMC / 64, HIDC / 64, EC), 256, 0, stream>>>(w2, w2t, HIDC, DIMC);

    gate_kernel<<<BN / 16, 256, 0, stream>>>(x, wg, raw, weights, maskf);
    capacity_kernel<<<BC * EC, 64, 0, stream>>>(raw, maskf, pos, pos_tok, density, proxy);
    build_kernel<<<BN * EC / 256, 256, 0, stream>>>(maskf, pos, pos_tok, heads, nxt, node_tok);
    gather_ei_kernel<<<EC * BC * CAPC / 4, 256, 0, stream>>>(x, heads, nxt, node_tok, ei_bf);

    for (int g = 0; g < ngroups; ++g) {
        const u16* Ag  = ei_bf + (size_t)g * EG * BC * CAPC * DIMC;
        const u16* B1g = w1t   + (size_t)g * EG * DIMC * HIDC;
        gemm_bt_kernel<1><<<dim3(HIDC / 128, (BC * CAPC) / 128, EG), 256, 0, stream>>>(
            Ag, B1g, hidden, BC * CAPC, HIDC, DIMC,
            (long)BC * CAPC * DIMC, (long)HIDC * DIMC, (long)BC * CAPC * HIDC);
        const u16* B2g = w2t + (size_t)g * EG * HIDC * DIMC;
        u16* Eg = eo_bf + (size_t)g * EG * BC * CAPC * DIMC;
        gemm_bt_kernel<0><<<dim3(DIMC / 128, (BC * CAPC) / 128, EG), 256, 0, stream>>>(
            hidden, B2g, Eg, BC * CAPC, DIMC, HIDC,
            (long)BC * CAPC * HIDC, (long)DIMC * HIDC, (long)BC * CAPC * DIMC);
    }

    combine_kernel<<<BN, 256, 0, stream>>>(eo_bf, weights, maskf, pos_tok, out);
    loss_kernel<<<1, BC * EC, 0, stream>>>(density, proxy, out + (size_t)BN * DIMC);
}